// Round 4
// baseline (16513.203 us; speedup 1.0000x reference)
//
#include <hip/hip_runtime.h>
#include <math.h>

// Grid-LSTM B=128,T=256,L=2,H=512. Persistent kernel, LDS-resident bf16 weights,
// device-scope counter dataflow. 256 blocks x 256 threads, 1 block/CU (LDS-forced).

typedef __attribute__((ext_vector_type(8))) short short8;
typedef __attribute__((ext_vector_type(4))) float floatx4;

static constexpr int Hn = 512, Bn = 128, Tn = 256;
static constexpr long BH = 65536;   // 128*512

// ws byte offsets
static constexpr long WT_OFF   = 0;                        // bf16 frag weights 4*2048*1024*2 = 16777216
static constexpr long H0A_OFF  = 16777216;                 // bf16 [2 parity][BH]
static constexpr long H0B_OFF  = H0A_OFF + 262144;         // bf16 [2][BH]
static constexpr long H1_OFF   = H0B_OFF + 262144;         // bf16 [2 par][2 layer][BH]
static constexpr long M1_OFF   = H1_OFF + 524288;          // f32 [2 layer][BH]
static constexpr long M0_OFF   = M1_OFF + 524288;          // f32 [2 parity][BH]
static constexpr long BS_OFF   = M0_OFF + 524288;          // f32 [4][2048]
static constexpr long CNT_OFF  = BS_OFF + 32768;           // int [4][256]
static constexpr long ZERO_BYTES = (CNT_OFF + 4096) - H1_OFF;

__device__ __forceinline__ unsigned short f2bf(float f) {
    unsigned u = __builtin_bit_cast(unsigned, f);
    unsigned r = u + 0x7FFFu + ((u >> 16) & 1u);
    return (unsigned short)(r >> 16);
}
__device__ __forceinline__ unsigned pk2(float a, float b) {
    return (unsigned)f2bf(a) | ((unsigned)f2bf(b) << 16);
}

// Wt frag layout: [cell][colblk 128][ks 32][lane 64][8], element (col=lane&15, k=ks*32+(lane>>4)*8+i)
// col c = g*4+jj -> n = g*512 + colblk*4 + jj ; k<512 -> Wih, else Whh
__global__ __launch_bounds__(256) void transform_w(const float* __restrict__ Wih,
                                                   const float* __restrict__ Whh,
                                                   unsigned short* __restrict__ Wt) {
    long idx = (long)blockIdx.x * 256 + threadIdx.x;   // < 8388608
    int i = (int)(idx & 7);
    int lane = (int)((idx >> 3) & 63);
    int ks = (int)((idx >> 9) & 31);
    int colblk = (int)((idx >> 14) & 127);
    int cell = (int)(idx >> 21);
    int c = lane & 15, q = lane >> 4;
    int g = c >> 2, jj = c & 3;
    int n = g * 512 + colblk * 4 + jj;
    int k = ks * 32 + q * 8 + i;
    const float* src = (k < 512) ? Wih : Whh;
    Wt[idx] = f2bf(src[((long)cell * 2048 + n) * 512 + (k & 511)]);
}

__global__ __launch_bounds__(256) void transform_b(const float* __restrict__ bih,
                                                   const float* __restrict__ bhh,
                                                   float* __restrict__ bsum) {
    int idx = blockIdx.x * 256 + threadIdx.x;   // < 8192
    bsum[idx] = bih[idx] + bhh[idx];
}

__device__ __forceinline__ void sigCnt(int* c) {
    __syncthreads();
    if (threadIdx.x == 0)
        __hip_atomic_fetch_add(c, 1, __ATOMIC_RELEASE, __HIP_MEMORY_SCOPE_AGENT);
}
__device__ __forceinline__ void waitCnt(const int* c) {
    if (threadIdx.x == 0) {
        while (__hip_atomic_load(c, __ATOMIC_ACQUIRE, __HIP_MEMORY_SCOPE_AGENT) < 128)
            __builtin_amdgcn_s_sleep(8);
    }
    __syncthreads();
}

// one K-half (16 k-steps) vs bf16 activations [128][512].
// act k index is OPERAND-LOCAL (ks*32); ksBase selects only the W rows.
__device__ __forceinline__ void gemm_bf(const unsigned short* act,
    const unsigned short* Wslot, int ksBase, int rowTop, int lane,
    floatx4& a0, floatx4& a1)
{
    const int m16 = lane & 15, q = lane >> 4;
    const unsigned short* r0 = act + (long)(rowTop + m16) * 512 + q * 8;
    const unsigned short* r1 = r0 + 16 * 512;
    #pragma unroll
    for (int ks = 0; ks < 16; ++ks) {
        short8 A0 = *(const short8*)(r0 + ks * 32);
        short8 A1 = *(const short8*)(r1 + ks * 32);
        short8 b  = *(const short8*)(Wslot + (ksBase + ks) * 512 + lane * 8);
        a0 = __builtin_amdgcn_mfma_f32_16x16x32_bf16(A0, b, a0, 0, 0, 0);
        a1 = __builtin_amdgcn_mfma_f32_16x16x32_bf16(A1, b, a1, 0, 0, 0);
    }
}

// h-half vs fp32 H0 external [b][t][h] (row stride 131072), W rows 16..31
__device__ __forceinline__ void gemm_h0(const float* baseT,   // H0in + t*512
    const unsigned short* Wslot, int rowTop, int lane,
    floatx4& a0, floatx4& a1)
{
    const int m16 = lane & 15, q = lane >> 4;
    const float* r0 = baseT + (long)(rowTop + m16) * 131072 + q * 8;
    const float* r1 = r0 + 16L * 131072;
    #pragma unroll
    for (int ks = 0; ks < 16; ++ks) {
        float4 u0 = *(const float4*)(r0 + ks * 32);
        float4 u1 = *(const float4*)(r0 + ks * 32 + 4);
        float4 v0 = *(const float4*)(r1 + ks * 32);
        float4 v1 = *(const float4*)(r1 + ks * 32 + 4);
        short8 A0, A1;
        ((unsigned*)&A0)[0] = pk2(u0.x, u0.y); ((unsigned*)&A0)[1] = pk2(u0.z, u0.w);
        ((unsigned*)&A0)[2] = pk2(u1.x, u1.y); ((unsigned*)&A0)[3] = pk2(u1.z, u1.w);
        ((unsigned*)&A1)[0] = pk2(v0.x, v0.y); ((unsigned*)&A1)[1] = pk2(v0.z, v0.w);
        ((unsigned*)&A1)[2] = pk2(v1.x, v1.y); ((unsigned*)&A1)[3] = pk2(v1.z, v1.w);
        short8 b = *(const short8*)(Wslot + (16 + ks) * 512 + lane * 8);
        a0 = __builtin_amdgcn_mfma_f32_16x16x32_bf16(A0, b, a0, 0, 0, 0);
        a1 = __builtin_amdgcn_mfma_f32_16x16x32_bf16(A1, b, a1, 0, 0, 0);
    }
}

struct EpiOut {
    const float* cPrev;              // stride 512, or null (zeros)
    float* cOut; long cOutStride;
    unsigned short* hBf;             // stride 512
    float* hFp; long hFpStride;      // or null
    float* fH; float* fM; int layer; int doFinal;
};

__device__ __forceinline__ void cell_epilogue(float* ebuf, const float* bs,
    floatx4 a0, floatx4 a1, int colblk, const EpiOut o)
{
    const int tid = threadIdx.x, lane = tid & 63, wid = tid >> 6;
    const int m16 = lane & 15, q = lane >> 4;
    __syncthreads();   // ebuf reuse guard
    #pragma unroll
    for (int r = 0; r < 4; ++r) ebuf[(wid * 32 + q * 4 + r) * 17 + m16] = a0[r];
    #pragma unroll
    for (int r = 0; r < 4; ++r) ebuf[(wid * 32 + 16 + q * 4 + r) * 17 + m16] = a1[r];
    __syncthreads();
    #pragma unroll
    for (int it = 0; it < 2; ++it) {
        int lin = tid * 2 + it;          // 0..511
        int row = lin >> 2, jj = lin & 3;
        float iv = ebuf[row * 17 + jj]      + bs[jj];
        float fv = ebuf[row * 17 + 4 + jj]  + bs[4 + jj];
        float gv = ebuf[row * 17 + 8 + jj]  + bs[8 + jj];
        float ov = ebuf[row * 17 + 12 + jj] + bs[12 + jj];
        int jglob = colblk * 4 + jj;
        float cold = o.cPrev ? o.cPrev[row * 512 + jglob] : 0.f;
        float si = 1.f / (1.f + expf(-iv));
        float sf = 1.f / (1.f + expf(-fv));
        float so = 1.f / (1.f + expf(-ov));
        float cn = sf * cold + si * tanhf(gv);
        float hn = so * tanhf(cn);
        o.hBf[row * 512 + jglob] = f2bf(hn);
        o.cOut[(long)row * o.cOutStride + jglob] = cn;
        if (o.hFp) o.hFp[(long)row * o.hFpStride + jglob] = hn;
        if (o.doFinal) {
            o.fH[(row * 2 + o.layer) * 512 + jglob] = hn;
            o.fM[(row * 2 + o.layer) * 512 + jglob] = cn;
        }
    }
}

__global__ void __launch_bounds__(256, 1) grid_lstm_persist(
    const float* __restrict__ H0in, const unsigned short* __restrict__ Wt,
    const float* __restrict__ bsum, unsigned short* h0A, unsigned short* h0B,
    unsigned short* H1bf, float* M1, float* m0buf, int* cnt,
    float* outH0, float* outH1, float* outM0, float* outM1)
{
    extern __shared__ char smem[];
    unsigned short* Wl = (unsigned short*)smem;            // [2 slots][32 ks][512]
    float* ebuf = (float*)(smem + 65536);                  // 128*17 = 8704 B
    float* bsL  = (float*)(smem + 65536 + 8704);           // [2][16]

    const int tid = threadIdx.x, lane = tid & 63, wid = tid >> 6;
    const int half = blockIdx.x >> 7, colblk = blockIdx.x & 127;
    const int cellA = half ? 3 : 0, cellB = half ? 2 : 1;
    const int rowTop = wid * 32;

    {   // one-time: W slices -> LDS, biases -> LDS
        const uint4* sA = (const uint4*)(Wt + ((long)(cellA * 128 + colblk) << 14));
        const uint4* sB = (const uint4*)(Wt + ((long)(cellB * 128 + colblk) << 14));
        uint4* dA = (uint4*)Wl; uint4* dB = (uint4*)(Wl + 16384);
        for (int i = tid; i < 2048; i += 256) { dA[i] = sA[i]; dB[i] = sB[i]; }
        if (tid < 32) {
            int s = tid >> 4, c = tid & 15, g = c >> 2, jj = c & 3;
            int cell = s ? cellB : cellA;
            bsL[tid] = bsum[cell * 2048 + g * 512 + colblk * 4 + jj];
        }
        __syncthreads();
    }
    const unsigned short* WA = Wl;
    const unsigned short* WB = Wl + 16384;
    const floatx4 z = {0.f, 0.f, 0.f, 0.f};

    for (int t = 0; t < Tn; ++t) {
        const int p = t & 1;
        unsigned short* H1old0 = H1bf + (long)p * 131072;
        unsigned short* H1old1 = H1old0 + 65536;
        unsigned short* H1new0 = H1bf + (long)(1 - p) * 131072;
        unsigned short* H1new1 = H1new0 + 65536;
        unsigned short* h0Ap = h0A + (long)p * BH;
        unsigned short* h0Bp = h0B + (long)p * BH;
        float* m0p = m0buf + (long)p * BH;

        if (half == 0) {
            // ---- c00: x=H1old[0] (Wih rows 0..15), h=H0[t] (Whh rows 16..31), c=0 ----
            floatx4 a0 = z, a1 = z;
            gemm_h0(H0in + (long)t * 512, WA, rowTop, lane, a0, a1);     // h-half (free)
            if (t > 0) waitCnt(&cnt[1 * 256 + t - 1]);                   // c01(t-1): H1old[0]
            gemm_bf(H1old0, WA, 0, rowTop, lane, a0, a1);                // x-half
            if (t > 1) waitCnt(&cnt[2 * 256 + t - 2]);                   // buffer safety h0A/m0
            cell_epilogue(ebuf, bsL, a0, a1, colblk,
                {nullptr, m0p, 512, h0Ap, nullptr, 0, nullptr, nullptr, 0, 0});
            sigCnt(&cnt[0 * 256 + t]);
            // ---- c01: x=h0A, h=H1old[0], c=M1[0] ----
            a0 = z; a1 = z;
            gemm_bf(H1old0, WB, 16, rowTop, lane, a0, a1);               // h-half (early)
            waitCnt(&cnt[0 * 256 + t]);                                  // h0A ready
            gemm_bf(h0Ap, WB, 0, rowTop, lane, a0, a1);                  // x-half
            cell_epilogue(ebuf, bsL + 16, a0, a1, colblk,
                {M1, M1, 512, H1new0, nullptr, 0, outH1, outM1, 0, t == Tn - 1});
            sigCnt(&cnt[1 * 256 + t]);
        } else {
            // ---- c10: x=H1old[1], h=h0A, c=m0 ----
            floatx4 a0 = z, a1 = z;
            if (t > 0) waitCnt(&cnt[3 * 256 + t - 1]);                   // c11(t-1): H1old[1]
            gemm_bf(H1old1, WB, 0, rowTop, lane, a0, a1);                // x-half (early)
            waitCnt(&cnt[0 * 256 + t]);                                  // h0A + m0 ready
            gemm_bf(h0Ap, WB, 16, rowTop, lane, a0, a1);                 // h-half
            cell_epilogue(ebuf, bsL + 16, a0, a1, colblk,
                {m0p, outM0 + (long)t * 512, 131072, h0Bp,
                 outH0 + (long)t * 512, 131072, nullptr, nullptr, 0, 0});
            sigCnt(&cnt[2 * 256 + t]);
            // ---- c11: x=h0B, h=H1old[1], c=M1[1] ----
            a0 = z; a1 = z;
            gemm_bf(H1old1, WA, 16, rowTop, lane, a0, a1);               // h-half (early)
            waitCnt(&cnt[2 * 256 + t]);                                  // h0B ready
            gemm_bf(h0Bp, WA, 0, rowTop, lane, a0, a1);                  // x-half
            cell_epilogue(ebuf, bsL, a0, a1, colblk,
                {M1 + BH, M1 + BH, 512, H1new1, nullptr, 0, outH1, outM1, 1, t == Tn - 1});
            sigCnt(&cnt[3 * 256 + t]);
        }
    }
}

extern "C" void kernel_launch(void* const* d_in, const int* in_sizes, int n_in,
                              void* d_out, int out_size, void* d_ws, size_t ws_size,
                              hipStream_t stream) {
    const float* H0in = (const float*)d_in[0];
    const float* Wih  = (const float*)d_in[1];
    const float* Whh  = (const float*)d_in[2];
    const float* bih  = (const float*)d_in[3];
    const float* bhh  = (const float*)d_in[4];
    float* out = (float*)d_out;
    char* ws = (char*)d_ws;

    unsigned short* Wt   = (unsigned short*)(ws + WT_OFF);
    unsigned short* h0A  = (unsigned short*)(ws + H0A_OFF);
    unsigned short* h0B  = (unsigned short*)(ws + H0B_OFF);
    unsigned short* H1bf = (unsigned short*)(ws + H1_OFF);
    float* M1   = (float*)(ws + M1_OFF);
    float* m0b  = (float*)(ws + M0_OFF);
    float* bsum = (float*)(ws + BS_OFF);
    int*   cnt  = (int*)(ws + CNT_OFF);

    hipMemsetAsync(ws + H1_OFF, 0, ZERO_BYTES, stream);
    transform_w<<<32768, 256, 0, stream>>>(Wih, Whh, Wt);
    transform_b<<<32, 256, 0, stream>>>(bih, bhh, bsum);

    float* outH0 = out;
    float* outH1 = out + 16777216L;            // B*T*H
    float* outM0 = outH1 + 131072L;            // B*L*H
    float* outM1 = outM0 + 16777216L;

    hipFuncSetAttribute((const void*)grid_lstm_persist,
                        hipFuncAttributeMaxDynamicSharedMemorySize, 86016);
    grid_lstm_persist<<<256, 256, 86016, stream>>>(
        H0in, Wt, bsum, h0A, h0B, H1bf, M1, m0b, cnt,
        outH0, outH1, outM0, outM1);
}